// Round 3
// baseline (387.019 us; speedup 1.0000x reference)
//
#include <hip/hip_runtime.h>

#define IRE (1.0f / 400.0f)

constexpr int W = 512;
constexpr int H = 512;
constexpr int NB = 64;
constexpr int ROWS = 8;
constexpr int CHUNKS = H / ROWS;   // 64
constexpr int GRID = NB * CHUNKS;  // 4096 single-wave blocks, full-row waves

struct Row {
    float4 tu0, tu1, tv0, tv1, pu0, pu1, pv0, pv1;
};

__device__ __forceinline__ void residuals3(
    float um, float vm, float ul, float vl, float ur, float vr,
    float ub, float vb, float ut, float vt,
    float& mass, float& momu, float& momv)
{
    float dudx = (ur - ul) * 0.5f;
    float dvdy = (vt - vb) * 0.5f;
    float ru = ur + um, lu = ul + um, tu_ = ut + um, bu = ub + um;
    float rv = vr + vm, lv = vl + vm, tv_ = vt + vm, bv = vb + vm;
    float du2dx = 0.25f * (ru * ru - lu * lu);
    float duvdy = 0.25f * (tu_ * tv_ - bu * bv);
    float dv2dy = 0.25f * (tv_ * tv_ - bv * bv);
    float dvudx = 0.25f * (rv * ru - lv * lu);
    float dudx2 = ur - 2.0f * um + ul;
    float dudy2 = ut - 2.0f * um + ub;
    float dvdx2 = vr - 2.0f * vm + vl;
    float dvdy2 = vt - 2.0f * vm + vb;
    mass = dudx + dvdy;
    momu = du2dx + duvdy - (dudx2 + dudy2) * IRE;
    momv = dvudx + dv2dy - (dvdx2 + dvdy2) * IRE;
}

__global__ __launch_bounds__(64, 4) void loss_main(
    const float* __restrict__ pred, const float* __restrict__ trut,
    double* __restrict__ partial)
{
    const int lane  = threadIdx.x;
    const int chunk = blockIdx.x % CHUNKS;
    const int b     = blockIdx.x / CHUNKS;
    const int r0 = chunk * ROWS;
    const int c0 = lane * 8;           // each lane owns 8 contiguous columns

    const size_t CH = (size_t)H * W;
    const float* g_tu = trut + (size_t)b * 2 * CH;
    const float* g_tv = g_tu + CH;
    const float* g_pu = pred + (size_t)b * 2 * CH;
    const float* g_pv = g_pu + CH;

    const int lo = (r0 > 0) ? r0 : 1;
    const int hi = (r0 + ROWS < H - 1) ? (r0 + ROWS) : (H - 1);

    float accMass = 0.0f, accMom = 0.0f, accL1 = 0.0f;

    Row P, X, N;   // rows i-1, i, i+1

    auto loadRow = [&](int r, Row& R, bool countL1) {
        const size_t off = (size_t)r * W + c0;
        R.tu0 = *(const float4*)(g_tu + off);  R.tu1 = *(const float4*)(g_tu + off + 4);
        R.tv0 = *(const float4*)(g_tv + off);  R.tv1 = *(const float4*)(g_tv + off + 4);
        R.pu0 = *(const float4*)(g_pu + off);  R.pu1 = *(const float4*)(g_pu + off + 4);
        R.pv0 = *(const float4*)(g_pv + off);  R.pv1 = *(const float4*)(g_pv + off + 4);
        if (countL1 && r >= r0 && r < r0 + ROWS) {  // each owned row counted exactly once
            accL1 += fabsf(R.pu0.x - R.tu0.x) + fabsf(R.pu0.y - R.tu0.y)
                   + fabsf(R.pu0.z - R.tu0.z) + fabsf(R.pu0.w - R.tu0.w)
                   + fabsf(R.pu1.x - R.tu1.x) + fabsf(R.pu1.y - R.tu1.y)
                   + fabsf(R.pu1.z - R.tu1.z) + fabsf(R.pu1.w - R.tu1.w)
                   + fabsf(R.pv0.x - R.tv0.x) + fabsf(R.pv0.y - R.tv0.y)
                   + fabsf(R.pv0.z - R.tv0.z) + fabsf(R.pv0.w - R.tv0.w)
                   + fabsf(R.pv1.x - R.tv1.x) + fabsf(R.pv1.y - R.tv1.y)
                   + fabsf(R.pv1.z - R.tv1.z) + fabsf(R.pv1.w - R.tv1.w);
        }
    };

    loadRow(lo - 1, P, true);
    loadRow(lo,     X, true);
    loadRow(lo + 1, N, true);

    for (int i = lo; i < hi; ++i) {
        Row Q;
        const bool pf = (i + 2 <= hi);
        // clamped duplicate load (cache hit) keeps control flow + load schedule uniform;
        // countL1=pf prevents double-counting the duplicated last row
        loadRow(pf ? (i + 2) : hi, Q, pf);

        // j-halo purely via +-1 lane shuffles; lane 0 / lane 63 edges are the
        // physical domain boundary (predicated off below) -> NO edge loads
        float Ltu = __shfl_up(X.tu1.w, 1), Rtu = __shfl_down(X.tu0.x, 1);
        float Ltv = __shfl_up(X.tv1.w, 1), Rtv = __shfl_down(X.tv0.x, 1);
        float Lpu = __shfl_up(X.pu1.w, 1), Rpu = __shfl_down(X.pu0.x, 1);
        float Lpv = __shfl_up(X.pv1.w, 1), Rpv = __shfl_down(X.pv0.x, 1);

        const float ctu[10] = {Ltu, X.tu0.x, X.tu0.y, X.tu0.z, X.tu0.w,
                                    X.tu1.x, X.tu1.y, X.tu1.z, X.tu1.w, Rtu};
        const float ctv[10] = {Ltv, X.tv0.x, X.tv0.y, X.tv0.z, X.tv0.w,
                                    X.tv1.x, X.tv1.y, X.tv1.z, X.tv1.w, Rtv};
        const float cpu_[10]= {Lpu, X.pu0.x, X.pu0.y, X.pu0.z, X.pu0.w,
                                    X.pu1.x, X.pu1.y, X.pu1.z, X.pu1.w, Rpu};
        const float cpv[10] = {Lpv, X.pv0.x, X.pv0.y, X.pv0.z, X.pv0.w,
                                    X.pv1.x, X.pv1.y, X.pv1.z, X.pv1.w, Rpv};
        const float ptu[8] = {P.tu0.x, P.tu0.y, P.tu0.z, P.tu0.w, P.tu1.x, P.tu1.y, P.tu1.z, P.tu1.w};
        const float ptv[8] = {P.tv0.x, P.tv0.y, P.tv0.z, P.tv0.w, P.tv1.x, P.tv1.y, P.tv1.z, P.tv1.w};
        const float ppu[8] = {P.pu0.x, P.pu0.y, P.pu0.z, P.pu0.w, P.pu1.x, P.pu1.y, P.pu1.z, P.pu1.w};
        const float ppv[8] = {P.pv0.x, P.pv0.y, P.pv0.z, P.pv0.w, P.pv1.x, P.pv1.y, P.pv1.z, P.pv1.w};
        const float ntu[8] = {N.tu0.x, N.tu0.y, N.tu0.z, N.tu0.w, N.tu1.x, N.tu1.y, N.tu1.z, N.tu1.w};
        const float ntv[8] = {N.tv0.x, N.tv0.y, N.tv0.z, N.tv0.w, N.tv1.x, N.tv1.y, N.tv1.z, N.tv1.w};
        const float npu[8] = {N.pu0.x, N.pu0.y, N.pu0.z, N.pu0.w, N.pu1.x, N.pu1.y, N.pu1.z, N.pu1.w};
        const float npv[8] = {N.pv0.x, N.pv0.y, N.pv0.z, N.pv0.w, N.pv1.x, N.pv1.y, N.pv1.z, N.pv1.w};

        #pragma unroll
        for (int k = 0; k < 8; ++k) {
            const int j = c0 + k;
            if (j >= 1 && j <= W - 2) {   // non-uniform only for lane0 k=0, lane63 k=7
                float mT, uT, vT, mP, uP, vP;
                residuals3(ctu[k+1], ctv[k+1], ptu[k], ptv[k], ntu[k], ntv[k],
                           ctu[k],   ctv[k],   ctu[k+2], ctv[k+2], mT, uT, vT);
                residuals3(cpu_[k+1], cpv[k+1], ppu[k], ppv[k], npu[k], npv[k],
                           cpu_[k],   cpv[k],   cpu_[k+2], cpv[k+2], mP, uP, vP);
                accMass += fabsf(mT - mP);
                accMom  += fabsf(uT - uP) + fabsf(vT - vP);
            }
        }

        P = X; X = N; N = Q;
    }

    float res = 5.0f * accMass + 25.0f * accMom;
    float l1  = accL1;
    #pragma unroll
    for (int off = 32; off > 0; off >>= 1) {
        res += __shfl_down(res, off);
        l1  += __shfl_down(l1, off);
    }
    if (lane == 0) {
        partial[(size_t)blockIdx.x * 2 + 0] = (double)res;
        partial[(size_t)blockIdx.x * 2 + 1] = (double)l1;
    }
}

__global__ __launch_bounds__(256) void loss_final(
    const double* __restrict__ partial, float* __restrict__ out)
{
    __shared__ double sres[4], sl1[4];
    const int t = threadIdx.x;
    double res = 0.0, l1 = 0.0;
    for (int i = t; i < GRID; i += 256) {
        res += partial[(size_t)i * 2 + 0];
        l1  += partial[(size_t)i * 2 + 1];
    }
    #pragma unroll
    for (int off = 32; off > 0; off >>= 1) {
        res += __shfl_down(res, off);
        l1  += __shfl_down(l1, off);
    }
    const int wave = t >> 6;
    if ((t & 63) == 0) { sres[wave] = res; sl1[wave] = l1; }
    __syncthreads();
    if (t == 0) {
        res = sres[0] + sres[1] + sres[2] + sres[3];
        l1  = sl1[0] + sl1[1] + sl1[2] + sl1[3];
        const double nRes = 64.0 * 510.0 * 510.0;
        const double nL1  = 64.0 * 2.0 * 512.0 * 512.0;
        out[0] = (float)((res / nRes + l1 / nL1) / 3.0);
    }
}

extern "C" void kernel_launch(void* const* d_in, const int* in_sizes, int n_in,
                              void* d_out, int out_size, void* d_ws, size_t ws_size,
                              hipStream_t stream)
{
    const float* pred = (const float*)d_in[0];
    const float* trut = (const float*)d_in[1];
    double* partial = (double*)d_ws;   // 4096*2 doubles = 64 KB, written before read
    loss_main<<<GRID, 64, 0, stream>>>(pred, trut, partial);
    loss_final<<<1, 256, 0, stream>>>(partial, (float*)d_out);
}

// Round 4
// 303.340 us; speedup vs baseline: 1.2759x; 1.2759x over previous
//
#include <hip/hip_runtime.h>

#define IRE (1.0f / 400.0f)

constexpr int W = 512;
constexpr int H = 512;
constexpr int NB = 64;
constexpr int ROWS = 8;
constexpr int CHUNKS = H / ROWS;               // 64
constexpr int STRIPS = 2;                      // 256 cols per strip, 4 per lane
constexpr int NWAVES = NB * CHUNKS * STRIPS;   // 8192
constexpr int WPB = 4;                         // independent waves per block
constexpr int GRID = NWAVES / WPB;             // 2048 blocks of 256 threads

struct Row  { float4 tu, tv, pu, pv; };
struct Edge { float ltu, ltv, lpu, lpv, rtu, rtv, rpu, rpv; };

__device__ __forceinline__ void residuals3(
    float um, float vm, float ul, float vl, float ur, float vr,
    float ub, float vb, float ut, float vt,
    float& mass, float& momu, float& momv)
{
    float dudx = (ur - ul) * 0.5f;
    float dvdy = (vt - vb) * 0.5f;
    float ru = ur + um, lu = ul + um, tu_ = ut + um, bu = ub + um;
    float rv = vr + vm, lv = vl + vm, tv_ = vt + vm, bv = vb + vm;
    float du2dx = 0.25f * (ru * ru - lu * lu);
    float duvdy = 0.25f * (tu_ * tv_ - bu * bv);
    float dv2dy = 0.25f * (tv_ * tv_ - bv * bv);
    float dvudx = 0.25f * (rv * ru - lv * lu);
    float dudx2 = ur - 2.0f * um + ul;
    float dudy2 = ut - 2.0f * um + ub;
    float dvdx2 = vr - 2.0f * vm + vl;
    float dvdy2 = vt - 2.0f * vm + vb;
    mass = dudx + dvdy;
    momu = du2dx + duvdy - (dudx2 + dudy2) * IRE;
    momv = dvudx + dv2dy - (dvdx2 + dvdy2) * IRE;
}

__global__ __launch_bounds__(256) void loss_main(
    const float* __restrict__ pred, const float* __restrict__ trut,
    double* __restrict__ partial)
{
    const int lane = threadIdx.x & 63;
    // wave-uniform (SGPR) decomposition: readfirstlane makes it provably uniform
    const int gw = __builtin_amdgcn_readfirstlane(
        (int)blockIdx.x * WPB + ((int)threadIdx.x >> 6));
    const int strip = gw % STRIPS;
    const int chunk = (gw / STRIPS) % CHUNKS;
    const int b     = gw / (STRIPS * CHUNKS);

    const int r0 = chunk * ROWS;
    const int js = strip * 256 + lane * 4;
    // wave-uniform strip-edge columns (clamped; boundary values are predicated off)
    const int colL = (strip == 0) ? 0 : strip * 256 - 1;
    const int colR = (strip == STRIPS - 1) ? (W - 1) : strip * 256 + 256;

    const size_t CH = (size_t)H * W;
    const float* g_tu = trut + (size_t)b * 2 * CH;
    const float* g_tv = g_tu + CH;
    const float* g_pu = pred + (size_t)b * 2 * CH;
    const float* g_pv = g_pu + CH;

    const int lo = (r0 > 0) ? r0 : 1;
    const int hi = (r0 + ROWS < H - 1) ? (r0 + ROWS) : (H - 1);

    float accMass = 0.0f, accMom = 0.0f, accL1 = 0.0f;

    Row P, X, N;        // rows i-1, i, i+1
    Edge EX, EN;        // strip-edge scalars for rows i, i+1 (SGPR broadcast)

    auto loadRow = [&](int r, Row& R) {
        const size_t off = (size_t)r * W + js;
        R.tu = *(const float4*)(g_tu + off);
        R.tv = *(const float4*)(g_tv + off);
        R.pu = *(const float4*)(g_pu + off);
        R.pv = *(const float4*)(g_pv + off);
    };
    auto loadEdges = [&](int r, Edge& E) {   // wave-uniform addresses -> scalar loads
        const size_t oL = (size_t)r * W + colL;
        const size_t oR = (size_t)r * W + colR;
        E.ltu = g_tu[oL]; E.ltv = g_tv[oL]; E.lpu = g_pu[oL]; E.lpv = g_pv[oL];
        E.rtu = g_tu[oR]; E.rtv = g_tv[oR]; E.rpu = g_pu[oR]; E.rpv = g_pv[oR];
    };
    auto l1row = [&](const Row& R) {
        accL1 += fabsf(R.pu.x - R.tu.x) + fabsf(R.pu.y - R.tu.y)
               + fabsf(R.pu.z - R.tu.z) + fabsf(R.pu.w - R.tu.w)
               + fabsf(R.pv.x - R.tv.x) + fabsf(R.pv.y - R.tv.y)
               + fabsf(R.pv.z - R.tv.z) + fabsf(R.pv.w - R.tv.w);
    };

    loadRow(lo - 1, P);
    loadRow(lo,     X);
    loadRow(lo + 1, N);
    loadEdges(lo,     EX);
    loadEdges(lo + 1, EN);

    if (r0 == 0) l1row(P);   // row 0 only ever occupies the P stage

    for (int i = lo; i < hi; ++i) {
        Row Q; Edge EQ;
        const bool pf = (i + 2 <= hi);
        const int rq = pf ? (i + 2) : hi;   // clamped duplicate keeps schedule uniform
        loadRow(rq, Q);
        loadEdges(rq, EQ);

        l1row(X);   // rows lo..hi-1: each owned row counted exactly once here

        // j-halo: +-1 lane shuffle, boundary lanes use the prefetched edge scalars
        float Ltu = __shfl_up(X.tu.w, 1), Rtu = __shfl_down(X.tu.x, 1);
        float Ltv = __shfl_up(X.tv.w, 1), Rtv = __shfl_down(X.tv.x, 1);
        float Lpu = __shfl_up(X.pu.w, 1), Rpu = __shfl_down(X.pu.x, 1);
        float Lpv = __shfl_up(X.pv.w, 1), Rpv = __shfl_down(X.pv.x, 1);
        if (lane == 0)  { Ltu = EX.ltu; Ltv = EX.ltv; Lpu = EX.lpu; Lpv = EX.lpv; }
        if (lane == 63) { Rtu = EX.rtu; Rtv = EX.rtv; Rpu = EX.rpu; Rpv = EX.rpv; }

        const float ctu[6] = {Ltu, X.tu.x, X.tu.y, X.tu.z, X.tu.w, Rtu};
        const float ctv[6] = {Ltv, X.tv.x, X.tv.y, X.tv.z, X.tv.w, Rtv};
        const float cpu_[6]= {Lpu, X.pu.x, X.pu.y, X.pu.z, X.pu.w, Rpu};
        const float cpv[6] = {Lpv, X.pv.x, X.pv.y, X.pv.z, X.pv.w, Rpv};
        const float ptu[4] = {P.tu.x, P.tu.y, P.tu.z, P.tu.w};
        const float ptv[4] = {P.tv.x, P.tv.y, P.tv.z, P.tv.w};
        const float ppu[4] = {P.pu.x, P.pu.y, P.pu.z, P.pu.w};
        const float ppv[4] = {P.pv.x, P.pv.y, P.pv.z, P.pv.w};
        const float ntu[4] = {N.tu.x, N.tu.y, N.tu.z, N.tu.w};
        const float ntv[4] = {N.tv.x, N.tv.y, N.tv.z, N.tv.w};
        const float npu[4] = {N.pu.x, N.pu.y, N.pu.z, N.pu.w};
        const float npv[4] = {N.pv.x, N.pv.y, N.pv.z, N.pv.w};

        #pragma unroll
        for (int k = 0; k < 4; ++k) {
            const int j = js + k;
            if (j >= 1 && j <= W - 2) {   // only lane0/k0 (strip0), lane63/k3 (strip1) off
                float mT, uT, vT, mP, uP, vP;
                residuals3(ctu[k+1], ctv[k+1], ptu[k], ptv[k], ntu[k], ntv[k],
                           ctu[k],   ctv[k],   ctu[k+2], ctv[k+2], mT, uT, vT);
                residuals3(cpu_[k+1], cpv[k+1], ppu[k], ppv[k], npu[k], npv[k],
                           cpu_[k],   cpv[k],   cpu_[k+2], cpv[k+2], mP, uP, vP);
                accMass += fabsf(mT - mP);
                accMom  += fabsf(uT - uP) + fabsf(vT - vP);
            }
        }

        P = X; X = N; N = Q;
        EX = EN; EN = EQ;
    }

    if (hi < r0 + ROWS) l1row(X);   // row hi (==511 on the last chunk) ends in X

    float res = 5.0f * accMass + 25.0f * accMom;
    float l1  = accL1;
    #pragma unroll
    for (int off = 32; off > 0; off >>= 1) {
        res += __shfl_down(res, off);
        l1  += __shfl_down(l1, off);
    }
    if (lane == 0) {   // independent per-wave partials; no barrier, no atomics
        partial[(size_t)gw * 2 + 0] = (double)res;
        partial[(size_t)gw * 2 + 1] = (double)l1;
    }
}

__global__ __launch_bounds__(256) void loss_final(
    const double* __restrict__ partial, float* __restrict__ out)
{
    __shared__ double sres[4], sl1[4];
    const int t = threadIdx.x;
    double res = 0.0, l1 = 0.0;
    for (int i = t; i < NWAVES; i += 256) {
        res += partial[(size_t)i * 2 + 0];
        l1  += partial[(size_t)i * 2 + 1];
    }
    #pragma unroll
    for (int off = 32; off > 0; off >>= 1) {
        res += __shfl_down(res, off);
        l1  += __shfl_down(l1, off);
    }
    const int wave = t >> 6;
    if ((t & 63) == 0) { sres[wave] = res; sl1[wave] = l1; }
    __syncthreads();
    if (t == 0) {
        res = sres[0] + sres[1] + sres[2] + sres[3];
        l1  = sl1[0] + sl1[1] + sl1[2] + sl1[3];
        const double nRes = 64.0 * 510.0 * 510.0;
        const double nL1  = 64.0 * 2.0 * 512.0 * 512.0;
        out[0] = (float)((res / nRes + l1 / nL1) / 3.0);
    }
}

extern "C" void kernel_launch(void* const* d_in, const int* in_sizes, int n_in,
                              void* d_out, int out_size, void* d_ws, size_t ws_size,
                              hipStream_t stream)
{
    const float* pred = (const float*)d_in[0];
    const float* trut = (const float*)d_in[1];
    double* partial = (double*)d_ws;   // 8192*2 doubles = 128 KB, written before read
    loss_main<<<GRID, 256, 0, stream>>>(pred, trut, partial);
    loss_final<<<1, 256, 0, stream>>>(partial, (float*)d_out);
}

// Round 5
// 291.049 us; speedup vs baseline: 1.3297x; 1.0422x over previous
//
#include <hip/hip_runtime.h>

#define IRE (1.0f / 400.0f)

constexpr int W = 512;
constexpr int H = 512;
constexpr int NB = 64;
constexpr int ROWS = 8;
constexpr int CHUNKS = H / ROWS;               // 64
constexpr int STRIPS = 2;                      // 256 cols per strip, 4 per lane
constexpr int NWAVES = NB * CHUNKS * STRIPS;   // 8192
constexpr int WPB = 4;                         // independent waves per block
constexpr int GRID = NWAVES / WPB;             // 2048 blocks of 256 threads

struct Row  { float4 tu, tv, pu, pv; };
struct Edge { float ltu, ltv, lpu, lpv, rtu, rtv, rpu, rpv; };

__device__ __forceinline__ void residuals3(
    float um, float vm, float ul, float vl, float ur, float vr,
    float ub, float vb, float ut, float vt,
    float& mass, float& momu, float& momv)
{
    float dudx = (ur - ul) * 0.5f;
    float dvdy = (vt - vb) * 0.5f;
    float ru = ur + um, lu = ul + um, tu_ = ut + um, bu = ub + um;
    float rv = vr + vm, lv = vl + vm, tv_ = vt + vm, bv = vb + vm;
    float du2dx = 0.25f * (ru * ru - lu * lu);
    float duvdy = 0.25f * (tu_ * tv_ - bu * bv);
    float dv2dy = 0.25f * (tv_ * tv_ - bv * bv);
    float dvudx = 0.25f * (rv * ru - lv * lu);
    float dudx2 = ur - 2.0f * um + ul;
    float dudy2 = ut - 2.0f * um + ub;
    float dvdx2 = vr - 2.0f * vm + vl;
    float dvdy2 = vt - 2.0f * vm + vb;
    mass = dudx + dvdy;
    momu = du2dx + duvdy - (dudx2 + dudy2) * IRE;
    momv = dvudx + dv2dy - (dvdx2 + dvdy2) * IRE;
}

__global__ __launch_bounds__(256) void loss_main(
    const float* __restrict__ pred, const float* __restrict__ trut,
    double* __restrict__ partial)
{
    const int tid  = (int)threadIdx.x;
    const int lane = tid & 63;
    // NO readfirstlane: keep these formally divergent so edge loads stay
    // VECTOR loads (scalarized s_load => SMEM is out-of-order => lgkmcnt(0)
    // drain on every use, which serialized round 4).
    const int gw    = (int)blockIdx.x * WPB + (tid >> 6);
    const int strip = gw % STRIPS;
    const int chunk = (gw / STRIPS) % CHUNKS;
    const int b     = gw / (STRIPS * CHUNKS);

    const int r0 = chunk * ROWS;
    const int js = strip * 256 + lane * 4;
    // strip-edge columns (clamped; the clamped side's values are predicated off)
    const int colL = (strip == 0) ? 0 : strip * 256 - 1;
    const int colR = (strip == STRIPS - 1) ? (W - 1) : strip * 256 + 256;

    const size_t CH = (size_t)H * W;
    const float* g_tu = trut + (size_t)b * 2 * CH;
    const float* g_tv = g_tu + CH;
    const float* g_pu = pred + (size_t)b * 2 * CH;
    const float* g_pv = g_pu + CH;

    const int lo = (r0 > 0) ? r0 : 1;
    const int hi = (r0 + ROWS < H - 1) ? (r0 + ROWS) : (H - 1);

    float accMass = 0.0f, accMom = 0.0f, accL1 = 0.0f;

    Row P, X, N;        // rows i-1, i, i+1
    Edge EX, EN;        // strip-edge values for rows i, i+1

    auto loadRow = [&](int r, Row& R) {
        const size_t off = (size_t)r * W + js;
        R.tu = *(const float4*)(g_tu + off);
        R.tv = *(const float4*)(g_tv + off);
        R.pu = *(const float4*)(g_pu + off);
        R.pv = *(const float4*)(g_pv + off);
    };
    // Unconditional, all-lanes-same-address VECTOR loads (HW broadcasts one
    // line). In-order vmcnt tracking lets the compiler wait with vmcnt(N>0),
    // keeping this iteration's prefetches in flight.
    auto loadEdges = [&](int r, Edge& E) {
        const size_t oL = (size_t)r * W + colL;
        const size_t oR = (size_t)r * W + colR;
        E.ltu = g_tu[oL]; E.ltv = g_tv[oL]; E.lpu = g_pu[oL]; E.lpv = g_pv[oL];
        E.rtu = g_tu[oR]; E.rtv = g_tv[oR]; E.rpu = g_pu[oR]; E.rpv = g_pv[oR];
    };
    auto l1row = [&](const Row& R) {
        accL1 += fabsf(R.pu.x - R.tu.x) + fabsf(R.pu.y - R.tu.y)
               + fabsf(R.pu.z - R.tu.z) + fabsf(R.pu.w - R.tu.w)
               + fabsf(R.pv.x - R.tv.x) + fabsf(R.pv.y - R.tv.y)
               + fabsf(R.pv.z - R.tv.z) + fabsf(R.pv.w - R.tv.w);
    };

    loadRow(lo - 1, P);
    loadRow(lo,     X);
    loadRow(lo + 1, N);
    loadEdges(lo,     EX);
    loadEdges(lo + 1, EN);

    if (r0 == 0) l1row(P);   // row 0 only ever occupies the P stage

    for (int i = lo; i < hi; ++i) {
        Row Q; Edge EQ;
        const bool pf = (i + 2 <= hi);
        const int rq = pf ? (i + 2) : hi;   // clamped duplicate keeps schedule uniform
        loadRow(rq, Q);
        loadEdges(rq, EQ);

        l1row(X);   // rows lo..hi-1: each owned row counted exactly once here

        // j-halo: +-1 lane shuffle; boundary lanes substitute the prefetched
        // edge values (v_cndmask, no branch, no load)
        float Ltu = __shfl_up(X.tu.w, 1), Rtu = __shfl_down(X.tu.x, 1);
        float Ltv = __shfl_up(X.tv.w, 1), Rtv = __shfl_down(X.tv.x, 1);
        float Lpu = __shfl_up(X.pu.w, 1), Rpu = __shfl_down(X.pu.x, 1);
        float Lpv = __shfl_up(X.pv.w, 1), Rpv = __shfl_down(X.pv.x, 1);
        if (lane == 0)  { Ltu = EX.ltu; Ltv = EX.ltv; Lpu = EX.lpu; Lpv = EX.lpv; }
        if (lane == 63) { Rtu = EX.rtu; Rtv = EX.rtv; Rpu = EX.rpu; Rpv = EX.rpv; }

        const float ctu[6] = {Ltu, X.tu.x, X.tu.y, X.tu.z, X.tu.w, Rtu};
        const float ctv[6] = {Ltv, X.tv.x, X.tv.y, X.tv.z, X.tv.w, Rtv};
        const float cpu_[6]= {Lpu, X.pu.x, X.pu.y, X.pu.z, X.pu.w, Rpu};
        const float cpv[6] = {Lpv, X.pv.x, X.pv.y, X.pv.z, X.pv.w, Rpv};
        const float ptu[4] = {P.tu.x, P.tu.y, P.tu.z, P.tu.w};
        const float ptv[4] = {P.tv.x, P.tv.y, P.tv.z, P.tv.w};
        const float ppu[4] = {P.pu.x, P.pu.y, P.pu.z, P.pu.w};
        const float ppv[4] = {P.pv.x, P.pv.y, P.pv.z, P.pv.w};
        const float ntu[4] = {N.tu.x, N.tu.y, N.tu.z, N.tu.w};
        const float ntv[4] = {N.tv.x, N.tv.y, N.tv.z, N.tv.w};
        const float npu[4] = {N.pu.x, N.pu.y, N.pu.z, N.pu.w};
        const float npv[4] = {N.pv.x, N.pv.y, N.pv.z, N.pv.w};

        #pragma unroll
        for (int k = 0; k < 4; ++k) {
            const int j = js + k;
            if (j >= 1 && j <= W - 2) {   // only lane0/k0 (strip0), lane63/k3 (strip1) off
                float mT, uT, vT, mP, uP, vP;
                residuals3(ctu[k+1], ctv[k+1], ptu[k], ptv[k], ntu[k], ntv[k],
                           ctu[k],   ctv[k],   ctu[k+2], ctv[k+2], mT, uT, vT);
                residuals3(cpu_[k+1], cpv[k+1], ppu[k], ppv[k], npu[k], npv[k],
                           cpu_[k],   cpv[k],   cpu_[k+2], cpv[k+2], mP, uP, vP);
                accMass += fabsf(mT - mP);
                accMom  += fabsf(uT - uP) + fabsf(vT - vP);
            }
        }

        P = X; X = N; N = Q;
        EX = EN; EN = EQ;
    }

    if (hi < r0 + ROWS) l1row(X);   // row hi (==511 on the last chunk) ends in X

    float res = 5.0f * accMass + 25.0f * accMom;
    float l1  = accL1;
    #pragma unroll
    for (int off = 32; off > 0; off >>= 1) {
        res += __shfl_down(res, off);
        l1  += __shfl_down(l1, off);
    }
    if (lane == 0) {   // independent per-wave partials; no barrier, no atomics
        partial[(size_t)gw * 2 + 0] = (double)res;
        partial[(size_t)gw * 2 + 1] = (double)l1;
    }
}

__global__ __launch_bounds__(256) void loss_final(
    const double* __restrict__ partial, float* __restrict__ out)
{
    __shared__ double sres[4], sl1[4];
    const int t = threadIdx.x;
    double res = 0.0, l1 = 0.0;
    for (int i = t; i < NWAVES; i += 256) {
        res += partial[(size_t)i * 2 + 0];
        l1  += partial[(size_t)i * 2 + 1];
    }
    #pragma unroll
    for (int off = 32; off > 0; off >>= 1) {
        res += __shfl_down(res, off);
        l1  += __shfl_down(l1, off);
    }
    const int wave = t >> 6;
    if ((t & 63) == 0) { sres[wave] = res; sl1[wave] = l1; }
    __syncthreads();
    if (t == 0) {
        res = sres[0] + sres[1] + sres[2] + sres[3];
        l1  = sl1[0] + sl1[1] + sl1[2] + sl1[3];
        const double nRes = 64.0 * 510.0 * 510.0;
        const double nL1  = 64.0 * 2.0 * 512.0 * 512.0;
        out[0] = (float)((res / nRes + l1 / nL1) / 3.0);
    }
}

extern "C" void kernel_launch(void* const* d_in, const int* in_sizes, int n_in,
                              void* d_out, int out_size, void* d_ws, size_t ws_size,
                              hipStream_t stream)
{
    const float* pred = (const float*)d_in[0];
    const float* trut = (const float*)d_in[1];
    double* partial = (double*)d_ws;   // 8192*2 doubles = 128 KB, written before read
    loss_main<<<GRID, 256, 0, stream>>>(pred, trut, partial);
    loss_final<<<1, 256, 0, stream>>>(partial, (float*)d_out);
}

// Round 6
// 286.350 us; speedup vs baseline: 1.3516x; 1.0164x over previous
//
#include <hip/hip_runtime.h>

#define IRE (1.0f / 400.0f)

constexpr int W = 512;
constexpr int H = 512;
constexpr int NB = 64;
constexpr int ROWS = 8;                        // compile-time trip count
constexpr int CHUNKS = H / ROWS;               // 64
constexpr int STRIPS = 2;                      // 256 cols per strip, 4 per lane
constexpr int NWAVES = NB * CHUNKS * STRIPS;   // 8192
constexpr int WPB = 4;
constexpr int GRID = NWAVES / WPB;             // 2048 blocks x 256 threads

struct RowT  { float4 tu, tv, pu, pv; };
struct EdgeT { float tu, tv, pu, pv; };        // ONE halo column per strip

__device__ __forceinline__ void residuals3(
    float um, float vm, float ul, float vl, float ur, float vr,
    float ub, float vb, float ut, float vt,
    float& mass, float& momu, float& momv)
{
    float dudx = (ur - ul) * 0.5f;
    float dvdy = (vt - vb) * 0.5f;
    float ru = ur + um, lu = ul + um, tu_ = ut + um, bu = ub + um;
    float rv = vr + vm, lv = vl + vm, tv_ = vt + vm, bv = vb + vm;
    float du2dx = 0.25f * (ru * ru - lu * lu);
    float duvdy = 0.25f * (tu_ * tv_ - bu * bv);
    float dv2dy = 0.25f * (tv_ * tv_ - bv * bv);
    float dvudx = 0.25f * (rv * ru - lv * lu);
    float dudx2 = ur - 2.0f * um + ul;
    float dudy2 = ut - 2.0f * um + ub;
    float dvdx2 = vr - 2.0f * vm + vl;
    float dvdy2 = vt - 2.0f * vm + vb;
    mass = dudx + dvdy;
    momu = du2dx + duvdy - (dudx2 + dudy2) * IRE;
    momv = dvudx + dv2dy - (dvdx2 + dvdy2) * IRE;
}

__global__ __launch_bounds__(256) void loss_main(
    const float* __restrict__ pred, const float* __restrict__ trut,
    double* __restrict__ partial)
{
    const int tid  = (int)threadIdx.x;
    const int lane = tid & 63;
    // no readfirstlane: edge-load addresses must stay formally divergent so they
    // remain VECTOR loads (scalarized s_load => out-of-order SMEM => lgkmcnt(0)
    // drain per iteration, the round-4 regression)
    const int gw    = (int)blockIdx.x * WPB + (tid >> 6);
    const int strip = gw % STRIPS;
    const int chunk = (gw / STRIPS) % CHUNKS;
    const int b     = gw / (STRIPS * CHUNKS);

    const int r0 = chunk * ROWS;
    const int js = strip * 256 + lane * 4;
    // the single halo column this strip needs (other side is the domain edge)
    const int colE = (strip == 0) ? 256 : 255;

    const size_t CH = (size_t)H * W;
    const float* g_tu = trut + (size_t)b * 2 * CH;
    const float* g_tv = g_tu + CH;
    const float* g_pu = pred + (size_t)b * 2 * CH;
    const float* g_pv = g_pu + CH;

    float accMass = 0.0f, accMom = 0.0f, accL1 = 0.0f;

    RowT  ring[5];    // rows indexed (r - (r0-1)) % 5 -- constants after unroll
    EdgeT ering[3];   // edge col for row r0+s at slot s % 3

    auto clampr = [](int r) { return r < 0 ? 0 : (r > H - 1 ? H - 1 : r); };
    auto loadRow = [&](int r, RowT& R) {
        const size_t off = (size_t)r * W + js;
        R.tu = *(const float4*)(g_tu + off);
        R.tv = *(const float4*)(g_tv + off);
        R.pu = *(const float4*)(g_pu + off);
        R.pv = *(const float4*)(g_pv + off);
    };
    auto loadEdge = [&](int r, EdgeT& E) {   // all-lanes-same-address broadcast
        const size_t o = (size_t)r * W + colE;
        E.tu = g_tu[o]; E.tv = g_tv[o]; E.pu = g_pu[o]; E.pv = g_pv[o];
    };
    auto l1row = [&](const RowT& R) {
        accL1 += fabsf(R.pu.x - R.tu.x) + fabsf(R.pu.y - R.tu.y)
               + fabsf(R.pu.z - R.tu.z) + fabsf(R.pu.w - R.tu.w)
               + fabsf(R.pv.x - R.tv.x) + fabsf(R.pv.y - R.tv.y)
               + fabsf(R.pv.z - R.tv.z) + fabsf(R.pv.w - R.tv.w);
    };

    // depth-2 prologue: rows r0-1..r0+2 (clamped), edges for rows r0, r0+1
    loadRow(clampr(r0 - 1), ring[0]);
    loadRow(r0,             ring[1]);
    loadRow(r0 + 1,         ring[2]);
    loadRow(r0 + 2,         ring[3]);
    loadEdge(r0,     ering[0]);
    loadEdge(r0 + 1, ering[1]);

    #pragma unroll
    for (int s = 0; s < ROWS; ++s) {
        // prefetches into fresh (renamed) slots; consumed 2-3 bodies later, so
        // the compiler can stagger vmcnt waits instead of draining per body
        if (s <= 5) loadRow(clampr(r0 + s + 3), ring[(s + 4) % 5]);
        if (s <= 5) loadEdge(r0 + s + 2, ering[(s + 2) % 3]);

        const RowT& Pr = ring[s % 5];         // row r-1
        const RowT& Xr = ring[(s + 1) % 5];   // row r (owned)
        const RowT& Nr = ring[(s + 2) % 5];   // row r+1

        l1row(Xr);   // every row 0..511 owned by exactly one (chunk,body): once

        const int r = r0 + s;
        if (r >= 1 && r <= H - 2) {           // wave-uniform row mask
            const EdgeT& E = ering[s % 3];

            float Ltu = __shfl_up(Xr.tu.w, 1), Rtu = __shfl_down(Xr.tu.x, 1);
            float Ltv = __shfl_up(Xr.tv.w, 1), Rtv = __shfl_down(Xr.tv.x, 1);
            float Lpu = __shfl_up(Xr.pu.w, 1), Rpu = __shfl_down(Xr.pu.x, 1);
            float Lpv = __shfl_up(Xr.pv.w, 1), Rpv = __shfl_down(Xr.pv.x, 1);
            // lane0's L is only real for strip1 (col255=E), lane63's R only for
            // strip0 (col256=E); the other case is j-masked below, so the
            // unconditional substitution is safe for both strips
            if (lane == 0)  { Ltu = E.tu; Ltv = E.tv; Lpu = E.pu; Lpv = E.pv; }
            if (lane == 63) { Rtu = E.tu; Rtv = E.tv; Rpu = E.pu; Rpv = E.pv; }

            const float ctu[6] = {Ltu, Xr.tu.x, Xr.tu.y, Xr.tu.z, Xr.tu.w, Rtu};
            const float ctv[6] = {Ltv, Xr.tv.x, Xr.tv.y, Xr.tv.z, Xr.tv.w, Rtv};
            const float cpu_[6]= {Lpu, Xr.pu.x, Xr.pu.y, Xr.pu.z, Xr.pu.w, Rpu};
            const float cpv[6] = {Lpv, Xr.pv.x, Xr.pv.y, Xr.pv.z, Xr.pv.w, Rpv};
            const float ptu[4] = {Pr.tu.x, Pr.tu.y, Pr.tu.z, Pr.tu.w};
            const float ptv[4] = {Pr.tv.x, Pr.tv.y, Pr.tv.z, Pr.tv.w};
            const float ppu[4] = {Pr.pu.x, Pr.pu.y, Pr.pu.z, Pr.pu.w};
            const float ppv[4] = {Pr.pv.x, Pr.pv.y, Pr.pv.z, Pr.pv.w};
            const float ntu[4] = {Nr.tu.x, Nr.tu.y, Nr.tu.z, Nr.tu.w};
            const float ntv[4] = {Nr.tv.x, Nr.tv.y, Nr.tv.z, Nr.tv.w};
            const float npu[4] = {Nr.pu.x, Nr.pu.y, Nr.pu.z, Nr.pu.w};
            const float npv[4] = {Nr.pv.x, Nr.pv.y, Nr.pv.z, Nr.pv.w};

            #pragma unroll
            for (int k = 0; k < 4; ++k) {
                const int j = js + k;
                if (j >= 1 && j <= W - 2) {  // only lane0/k0 (strip0), lane63/k3 (strip1)
                    float mT, uT, vT, mP, uP, vP;
                    residuals3(ctu[k+1], ctv[k+1], ptu[k], ptv[k], ntu[k], ntv[k],
                               ctu[k],   ctv[k],   ctu[k+2], ctv[k+2], mT, uT, vT);
                    residuals3(cpu_[k+1], cpv[k+1], ppu[k], ppv[k], npu[k], npv[k],
                               cpu_[k],   cpv[k],   cpu_[k+2], cpv[k+2], mP, uP, vP);
                    accMass += fabsf(mT - mP);
                    accMom  += fabsf(uT - uP) + fabsf(vT - vP);
                }
            }
        }
    }

    float res = 5.0f * accMass + 25.0f * accMom;
    float l1  = accL1;
    #pragma unroll
    for (int off = 32; off > 0; off >>= 1) {
        res += __shfl_down(res, off);
        l1  += __shfl_down(l1, off);
    }
    if (lane == 0) {
        partial[(size_t)gw * 2 + 0] = (double)res;
        partial[(size_t)gw * 2 + 1] = (double)l1;
    }
}

__global__ __launch_bounds__(256) void loss_final(
    const double* __restrict__ partial, float* __restrict__ out)
{
    __shared__ double sres[4], sl1[4];
    const int t = threadIdx.x;
    double res = 0.0, l1 = 0.0;
    for (int i = t; i < NWAVES; i += 256) {
        res += partial[(size_t)i * 2 + 0];
        l1  += partial[(size_t)i * 2 + 1];
    }
    #pragma unroll
    for (int off = 32; off > 0; off >>= 1) {
        res += __shfl_down(res, off);
        l1  += __shfl_down(l1, off);
    }
    const int wave = t >> 6;
    if ((t & 63) == 0) { sres[wave] = res; sl1[wave] = l1; }
    __syncthreads();
    if (t == 0) {
        res = sres[0] + sres[1] + sres[2] + sres[3];
        l1  = sl1[0] + sl1[1] + sl1[2] + sl1[3];
        const double nRes = 64.0 * 510.0 * 510.0;
        const double nL1  = 64.0 * 2.0 * 512.0 * 512.0;
        out[0] = (float)((res / nRes + l1 / nL1) / 3.0);
    }
}

extern "C" void kernel_launch(void* const* d_in, const int* in_sizes, int n_in,
                              void* d_out, int out_size, void* d_ws, size_t ws_size,
                              hipStream_t stream)
{
    const float* pred = (const float*)d_in[0];
    const float* trut = (const float*)d_in[1];
    double* partial = (double*)d_ws;   // 8192*2 doubles = 128 KB, written before read
    loss_main<<<GRID, 256, 0, stream>>>(pred, trut, partial);
    loss_final<<<1, 256, 0, stream>>>(partial, (float*)d_out);
}